// Round 1
// baseline (1537.082 us; speedup 1.0000x reference)
//
#include <hip/hip_runtime.h>
#include <math.h>

// Model dims
#define BB     32
#define DD     768
#define DIi    1536
#define DCONVi 1792
#define NHi    8
#define HDi    192
#define DSi    128
#define NCi    100
#define RIN    3336   // 2*DI + 2*DS + NH
#define NLAYER 12

static __device__ __forceinline__ float siluf(float x) { return x / (1.0f + expf(-x)); }

// ---------------------------------------------------------------------------
// K1: patch embed + assemble conv0 input (B,D,10) = [cnn_state[0] (4) | h (6)]
// ---------------------------------------------------------------------------
__global__ __launch_bounds__(256) void k_patch(const float* __restrict__ x,
                                               const float* __restrict__ pw,
                                               const float* __restrict__ pb,
                                               const float* __restrict__ cst0,
                                               float* __restrict__ cin0) {
  int idx = blockIdx.x * 256 + threadIdx.x;
  if (idx >= BB * DD * 10) return;
  int l = idx % 10;
  int d = (idx / 10) % DD;
  int b = idx / (10 * DD);
  float v;
  if (l < 4) {
    v = cst0[(b * DD + d) * 4 + l];
  } else {
    int w = l - 4;
    float acc = pb[d];
#pragma unroll
    for (int p = 0; p < 16; p++) acc += x[b * 96 + p * 6 + w] * pw[d * 16 + p];
    v = acc;
  }
  cin0[idx] = v;
}

// ---------------------------------------------------------------------------
// K2: conv layer as split-K GEMM. out[d, b*LOUT+l] partial over di-slice.
// grid (48, 16): m-block of 16 douts x K-split 16 (48 di each). block 128.
// part layout: [16][768][B*LOUT]
// ---------------------------------------------------------------------------
template <int LIN, int LOUT>
__global__ __launch_bounds__(128) void k_conv(const float* __restrict__ cin,
                                              const float* __restrict__ w,
                                              float* __restrict__ part) {
  const int NN = BB * LOUT;
  __shared__ float Wl[16][8][5];
  __shared__ float Il[8][BB][LIN];
  int tid = threadIdx.x;
  int m0 = blockIdx.x * 16;
  int di0 = blockIdx.y * 48;
  int tm = tid >> 4;  // 0..7
  int tb = tid & 15;  // 0..15
  float acc[2][2][LOUT] = {};

  for (int cc = 0; cc < 6; cc++) {
    int dib = di0 + cc * 8;
    {  // stage weights: 16m x 8di x 5k
      int m = tid >> 3, di = tid & 7;
      const float* wp = w + (size_t)(m0 + m) * (DD * 5) + (dib + di) * 5;
#pragma unroll
      for (int k = 0; k < 5; k++) Wl[m][di][k] = wp[k];
    }
#pragma unroll
    for (int j = 0; j < 2; j++) {  // stage input: 8di x 32b x LIN
      int flat = tid + 128 * j;
      int di = flat >> 5, b = flat & 31;
      const float* ip = cin + (size_t)(b * DD + dib + di) * LIN;
#pragma unroll
      for (int l = 0; l < LIN; l++) Il[di][b][l] = ip[l];
    }
    __syncthreads();
#pragma unroll
    for (int di = 0; di < 8; di++) {
      float a0[LIN], a1[LIN];
#pragma unroll
      for (int l = 0; l < LIN; l++) { a0[l] = Il[di][2 * tb][l]; a1[l] = Il[di][2 * tb + 1][l]; }
      float w0[5], w1[5];
#pragma unroll
      for (int k = 0; k < 5; k++) { w0[k] = Wl[2 * tm][di][k]; w1[k] = Wl[2 * tm + 1][di][k]; }
#pragma unroll
      for (int l = 0; l < LOUT; l++)
#pragma unroll
        for (int k = 0; k < 5; k++) {
          acc[0][0][l] += w0[k] * a0[l + k];
          acc[0][1][l] += w0[k] * a1[l + k];
          acc[1][0][l] += w1[k] * a0[l + k];
          acc[1][1][l] += w1[k] * a1[l + k];
        }
    }
    __syncthreads();
  }
#pragma unroll
  for (int mm = 0; mm < 2; mm++)
#pragma unroll
    for (int bb2 = 0; bb2 < 2; bb2++)
#pragma unroll
      for (int l = 0; l < LOUT; l++) {
        int d_ = m0 + 2 * tm + mm;
        int n = (2 * tb + bb2) * LOUT + l;
        part[((size_t)blockIdx.y * DD + d_) * NN + n] = acc[mm][bb2][l];
      }
}

// ---------------------------------------------------------------------------
// K3: sum partials + bias + BN + relu + pool; write next conv input (with state
// prefix) or final tok (+pos_embed).
// ---------------------------------------------------------------------------
__global__ __launch_bounds__(256) void k_bnrelu(const float* __restrict__ part, int LOUT, int PF,
                                                const float* __restrict__ cb,
                                                const float* __restrict__ bg,
                                                const float* __restrict__ bbeta,
                                                const float* __restrict__ rm,
                                                const float* __restrict__ rv, int mode,
                                                float* __restrict__ outp, int LINn,
                                                const float* __restrict__ stn,
                                                const float* __restrict__ pos,
                                                const int* __restrict__ pidx) {
  int idx = blockIdx.x * 256 + threadIdx.x;
  if (idx >= BB * DD) return;
  int d = idx % DD, b = idx / DD;
  int NN = BB * LOUT;
  float inv = rsqrtf(rv[d] + 1e-5f);
  float v[6];
  for (int l = 0; l < LOUT; l++) {
    float s = cb[d];
    for (int ss = 0; ss < 16; ss++) s += part[((size_t)ss * DD + d) * NN + b * LOUT + l];
    s = (s - rm[d]) * inv * bg[d] + bbeta[d];
    v[l] = fmaxf(s, 0.0f);
  }
  int LP = LOUT / PF;
  float pm[6];
  for (int lp = 0; lp < LP; lp++) {
    float m = v[lp * PF];
    for (int j = 1; j < PF; j++) m = fmaxf(m, v[lp * PF + j]);
    pm[lp] = m;
  }
  if (mode == 0) {
    float* o = outp + (size_t)(b * DD + d) * LINn;
    for (int j = 0; j < 4; j++) o[j] = stn[(b * DD + d) * 4 + j];
    for (int lp = 0; lp < LP; lp++) o[4 + lp] = pm[lp];
  } else {
    int clip = min(*pidx, 299);
    outp[b * DD + d] = pm[0] + pos[(1 + clip) * DD + d];
  }
}

// ---------------------------------------------------------------------------
// K4: in_proj GEMM, split-K=4. Reads tokrd (+ sum of dp partials when use_dp),
// writes zx partials [4][32][3336]; blocks bx==by write updated tok to tokwr.
// Block (0,0) re-zeroes sq[32] for this layer's SSM atomics.
// grid (105,4), block 128.
// ---------------------------------------------------------------------------
__global__ __launch_bounds__(128) void k_inproj(const float* __restrict__ W,
                                                const float* __restrict__ tokrd,
                                                const float* __restrict__ dp, int use_dp,
                                                float* __restrict__ tokwr,
                                                float* __restrict__ zx, float* __restrict__ sq) {
  __shared__ float Wl[64][36];
  __shared__ float Tl[64][36];
  int tid = threadIdx.x;
  int m0 = blockIdx.x * 32;
  int by = blockIdx.y;
  if (blockIdx.x == 0 && by == 0 && tid < 32) sq[tid] = 0.0f;
  int tm = tid & 15, tb = tid >> 4;  // tm 0..15, tb 0..7
  float acc[2][4] = {};
  for (int c = 0; c < 3; c++) {
    int k0 = by * 192 + c * 64;
#pragma unroll
    for (int j = 0; j < 4; j++) {  // stage W (transposed)
      int flat = tid + 128 * j;
      int m = flat >> 4, kf = flat & 15;
      float4 w4 = {0.f, 0.f, 0.f, 0.f};
      if (m0 + m < RIN) w4 = *(const float4*)(W + (size_t)(m0 + m) * DD + k0 + kf * 4);
      Wl[kf * 4 + 0][m] = w4.x; Wl[kf * 4 + 1][m] = w4.y;
      Wl[kf * 4 + 2][m] = w4.z; Wl[kf * 4 + 3][m] = w4.w;
    }
#pragma unroll
    for (int j = 0; j < 4; j++) {  // stage tok (+ lazy residual partials)
      int flat = tid + 128 * j;
      int b = flat >> 4, kf = flat & 15;
      int off = b * DD + k0 + kf * 4;
      float4 t4 = *(const float4*)(tokrd + off);
      if (use_dp) {
#pragma unroll
        for (int s = 0; s < 4; s++) {
          float4 d4 = *(const float4*)(dp + (size_t)s * (BB * DD) + off);
          t4.x += d4.x; t4.y += d4.y; t4.z += d4.z; t4.w += d4.w;
        }
        if ((int)blockIdx.x == by) *(float4*)(tokwr + off) = t4;
      }
      Tl[kf * 4 + 0][b] = t4.x; Tl[kf * 4 + 1][b] = t4.y;
      Tl[kf * 4 + 2][b] = t4.z; Tl[kf * 4 + 3][b] = t4.w;
    }
    __syncthreads();
#pragma unroll 4
    for (int kk = 0; kk < 64; kk++) {
      float2 wv = *(const float2*)&Wl[kk][2 * tm];
      float4 tv = *(const float4*)&Tl[kk][4 * tb];
      acc[0][0] += wv.x * tv.x; acc[0][1] += wv.x * tv.y;
      acc[0][2] += wv.x * tv.z; acc[0][3] += wv.x * tv.w;
      acc[1][0] += wv.y * tv.x; acc[1][1] += wv.y * tv.y;
      acc[1][2] += wv.y * tv.z; acc[1][3] += wv.y * tv.w;
    }
    __syncthreads();
  }
#pragma unroll
  for (int mm = 0; mm < 2; mm++)
#pragma unroll
    for (int b2 = 0; b2 < 4; b2++) {
      int r = m0 + 2 * tm + mm;
      if (r < RIN) zx[((size_t)by * BB + 4 * tb + b2) * RIN + r] = acc[mm][b2];
    }
}

// ---------------------------------------------------------------------------
// K5: SSM. grid 768 = b(32) x h(8) x pchunk(3 of 64). block 256 (4 waves).
// Prologue: conv-gate Bm/Cm/xh, silu(z), dt/dA, bc = Bm.Cm. Then wave-per-row
// contraction of ssm_state with Cm; y = dA*S + (dt*bc + D)*xh.
// Also atomically accumulates sum of (y*silu(z))^2 per batch into sq[b].
// ---------------------------------------------------------------------------
__global__ __launch_bounds__(256) void k_ssm(const float* __restrict__ zx,
                                             const float* __restrict__ ssm,
                                             const float* __restrict__ cst,
                                             const float* __restrict__ cw,
                                             const float* __restrict__ cb,
                                             const float* __restrict__ alog,
                                             const float* __restrict__ dtb,
                                             const float* __restrict__ dpar,
                                             float* __restrict__ y, float* __restrict__ sq) {
  int bx = blockIdx.x;
  int b = bx / 24;
  int rem = bx % 24;
  int h = rem / 3;
  int pc = rem % 3;
  int p0 = pc * 64;
  __shared__ float Cl[DSi], Bl[DSi], pl[DSi], xhl[64], zsl[64];
  __shared__ float s_dt, s_dA, s_coef;
  __shared__ float sqw[4];
  int tid = threadIdx.x;

  // conv gate helper: c is DCONV channel index
  auto convgate = [&](int c) -> float {
    float zr = 0.f;
#pragma unroll
    for (int s = 0; s < 4; s++) zr += zx[(size_t)s * (BB * RIN) + b * RIN + (DIi + c)];
    const float* cs = cst + (size_t)(b * DCONVi + c) * 4;
    const float* wc = cw + (size_t)c * 4;
    float v = cs[1] * wc[0] + cs[2] * wc[1] + cs[3] * wc[2] + zr * wc[3] + cb[c];
    return siluf(v);
  };

  if (tid < 128) Cl[tid] = convgate(DIi + DSi + tid);
  else Bl[tid - 128] = convgate(DIi + (tid - 128));
  __syncthreads();
  if (tid < 128) {
    pl[tid] = Bl[tid] * Cl[tid];
  } else if (tid < 192) {
    int p = tid - 128;
    xhl[p] = convgate(h * HDi + p0 + p);
  } else {
    int p = tid - 192;
    float zr = 0.f;
#pragma unroll
    for (int s = 0; s < 4; s++) zr += zx[(size_t)s * (BB * RIN) + b * RIN + (h * HDi + p0 + p)];
    zsl[p] = siluf(zr);
  }
  if (tid == 0) {
    float zr = 0.f;
#pragma unroll
    for (int s = 0; s < 4; s++) zr += zx[(size_t)s * (BB * RIN) + b * RIN + (DIi + DCONVi + h)];
    float xdt = zr + dtb[h];
    float dt = fmaxf(xdt, 0.f) + log1pf(expf(-fabsf(xdt)));  // softplus (stable)
    s_dt = dt;
    s_dA = expf(-expf(alog[h]) * dt);
  }
  __syncthreads();
  if (tid < 64) {
    float v = pl[tid] + pl[tid + 64];
#pragma unroll
    for (int m = 1; m < 64; m <<= 1) v += __shfl_xor(v, m, 64);
    if (tid == 0) s_coef = s_dt * v + dpar[h];
  }
  __syncthreads();

  float dA = s_dA, coef = s_coef;
  int wv = tid >> 6, lane = tid & 63;
  float c0 = Cl[2 * lane], c1 = Cl[2 * lane + 1];
  float gsq = 0.f;
  const float* sb = ssm + (size_t)((b * NHi + h) * HDi) * DSi;
  for (int i = 0; i < 16; i++) {
    int p = p0 + wv * 16 + i;
    float2 v = *(const float2*)(sb + (size_t)p * DSi + 2 * lane);
    float s = v.x * c0 + v.y * c1;
#pragma unroll
    for (int m = 1; m < 64; m <<= 1) s += __shfl_xor(s, m, 64);
    float yv = dA * s + coef * xhl[p - p0];
    if (lane == 0) {
      y[b * DIi + h * HDi + p] = yv;
      float g = yv * zsl[p - p0];
      gsq += g * g;
    }
  }
  if (lane == 0) sqw[wv] = gsq;
  __syncthreads();
  if (tid == 0) atomicAdd(&sq[b], sqw[0] + sqw[1] + sqw[2] + sqw[3]);
}

// ---------------------------------------------------------------------------
// K6: out_proj GEMM with fused gate+RMSnorm on staging. Split-K=4 writes
// residual-delta partials dp[4][32][768]. grid (48,4), block 128.
// ---------------------------------------------------------------------------
__global__ __launch_bounds__(128) void k_outproj(const float* __restrict__ W,
                                                 const float* __restrict__ y,
                                                 const float* __restrict__ zx,
                                                 const float* __restrict__ sq,
                                                 const float* __restrict__ nw,
                                                 float* __restrict__ dp) {
  __shared__ float Wl[64][20];
  __shared__ float Gl[64][36];
  __shared__ float sl[BB];
  int tid = threadIdx.x;
  if (tid < BB) sl[tid] = rsqrtf(sq[tid] * (1.0f / (float)DIi) + 1e-5f);
  __syncthreads();
  int m0 = blockIdx.x * 16, by = blockIdx.y;
  int tm = tid & 7, tb = tid >> 3;  // tm 0..7, tb 0..15
  float acc[2][2] = {};
  for (int c = 0; c < 6; c++) {
    int k0 = by * 384 + c * 64;
#pragma unroll
    for (int j = 0; j < 2; j++) {  // stage W
      int flat = tid + 128 * j;
      int m = flat >> 4, kf = flat & 15;
      float4 w4 = *(const float4*)(W + (size_t)(m0 + m) * DIi + k0 + kf * 4);
      Wl[kf * 4 + 0][m] = w4.x; Wl[kf * 4 + 1][m] = w4.y;
      Wl[kf * 4 + 2][m] = w4.z; Wl[kf * 4 + 3][m] = w4.w;
    }
#pragma unroll
    for (int j = 0; j < 4; j++) {  // stage g = y*silu(z)*scale*norm_w
      int flat = tid + 128 * j;
      int b = flat >> 4, kf = flat & 15;
      int k = k0 + kf * 4;
      float4 y4 = *(const float4*)(y + b * DIi + k);
      float4 z4 = {0.f, 0.f, 0.f, 0.f};
#pragma unroll
      for (int s = 0; s < 4; s++) {
        float4 t = *(const float4*)(zx + (size_t)s * (BB * RIN) + b * RIN + k);
        z4.x += t.x; z4.y += t.y; z4.z += t.z; z4.w += t.w;
      }
      float4 n4 = *(const float4*)(nw + k);
      float sc = sl[b];
      Gl[kf * 4 + 0][b] = y4.x * siluf(z4.x) * sc * n4.x;
      Gl[kf * 4 + 1][b] = y4.y * siluf(z4.y) * sc * n4.y;
      Gl[kf * 4 + 2][b] = y4.z * siluf(z4.z) * sc * n4.z;
      Gl[kf * 4 + 3][b] = y4.w * siluf(z4.w) * sc * n4.w;
    }
    __syncthreads();
#pragma unroll 4
    for (int kk = 0; kk < 64; kk++) {
      float2 w2 = *(const float2*)&Wl[kk][2 * tm];
      float2 g2 = *(const float2*)&Gl[kk][2 * tb];
      acc[0][0] += w2.x * g2.x; acc[0][1] += w2.x * g2.y;
      acc[1][0] += w2.y * g2.x; acc[1][1] += w2.y * g2.y;
    }
    __syncthreads();
  }
#pragma unroll
  for (int mm = 0; mm < 2; mm++)
#pragma unroll
    for (int b2 = 0; b2 < 2; b2++)
      dp[((size_t)by * BB + 2 * tb + b2) * DD + m0 + 2 * tm + mm] = acc[mm][b2];
}

// ---------------------------------------------------------------------------
// K7: final layernorm + history update + logits. grid 32 (per batch), block 256.
// out = [logits (32x100) | history (32x768)]
// ---------------------------------------------------------------------------
__global__ __launch_bounds__(256) void k_final(const float* __restrict__ tok,
                                               const float* __restrict__ dp,
                                               const float* __restrict__ hf,
                                               const float* __restrict__ fg,
                                               const float* __restrict__ fb,
                                               const float* __restrict__ fcw,
                                               const float* __restrict__ fcb,
                                               const int* __restrict__ pidx,
                                               float* __restrict__ out) {
  __shared__ float tl[DD], hl[DD], red1[4], red2[4];
  int b = blockIdx.x, tid = threadIdx.x;
  int wv = tid >> 6, lane = tid & 63;
  float psum = 0.f;
  for (int d = tid; d < DD; d += 256) {
    float v = tok[b * DD + d];
#pragma unroll
    for (int s = 0; s < 4; s++) v += dp[(size_t)s * (BB * DD) + b * DD + d];
    tl[d] = v;
    psum += v;
  }
#pragma unroll
  for (int m = 1; m < 64; m <<= 1) psum += __shfl_xor(psum, m, 64);
  if (lane == 0) red1[wv] = psum;
  __syncthreads();
  float mu = (red1[0] + red1[1] + red1[2] + red1[3]) * (1.0f / (float)DD);
  float vsum = 0.f;
  for (int d = tid; d < DD; d += 256) {
    float dd = tl[d] - mu;
    vsum += dd * dd;
  }
#pragma unroll
  for (int m = 1; m < 64; m <<= 1) vsum += __shfl_xor(vsum, m, 64);
  if (lane == 0) red2[wv] = vsum;
  __syncthreads();
  float var = (red2[0] + red2[1] + red2[2] + red2[3]) * (1.0f / (float)DD);
  float inv = rsqrtf(var + 1e-5f);
  float pi = (float)(*pidx);
  for (int d = tid; d < DD; d += 256) {
    float tn = (tl[d] - mu) * inv * fg[d] + fb[d];
    float hv = (hf[b * DD + d] * pi + tn) / (pi + 1.0f);
    hl[d] = hv;
    out[BB * NCi + b * DD + d] = hv;
  }
  __syncthreads();
  for (int n = wv; n < NCi; n += 4) {
    float s = 0.f;
    for (int d = lane; d < DD; d += 64) s += hl[d] * fcw[(size_t)n * DD + d];
#pragma unroll
    for (int m = 1; m < 64; m <<= 1) s += __shfl_xor(s, m, 64);
    if (lane == 0) out[b * NCi + n] = s + fcb[n];
  }
}

// ---------------------------------------------------------------------------
extern "C" void kernel_launch(void* const* d_in, const int* in_sizes, int n_in,
                              void* d_out, int out_size, void* d_ws, size_t ws_size,
                              hipStream_t stream) {
  const float* x       = (const float*)d_in[0];
  const float* hf      = (const float*)d_in[1];
  const float* patch_w = (const float*)d_in[2];
  const float* patch_b = (const float*)d_in[3];
  const float* cnn_w   = (const float*)d_in[4];
  const float* cnn_b   = (const float*)d_in[5];
  const float* bn_g    = (const float*)d_in[6];
  const float* bn_b    = (const float*)d_in[7];
  const float* bn_rm   = (const float*)d_in[8];
  const float* bn_rv   = (const float*)d_in[9];
  const float* cnn_st  = (const float*)d_in[10];
  const float* pos     = (const float*)d_in[11];
  const float* ipw     = (const float*)d_in[12];
  const float* cw      = (const float*)d_in[13];
  const float* cb1     = (const float*)d_in[14];
  const float* alog    = (const float*)d_in[15];
  const float* dtb     = (const float*)d_in[16];
  const float* dpar    = (const float*)d_in[17];
  const float* nw      = (const float*)d_in[18];
  const float* opw     = (const float*)d_in[19];
  const float* mcs     = (const float*)d_in[20];
  const float* ssm     = (const float*)d_in[21];
  const float* fcn_g   = (const float*)d_in[22];
  const float* fcn_b   = (const float*)d_in[23];
  const float* fc_w    = (const float*)d_in[24];
  const float* fc_b    = (const float*)d_in[25];
  const int*   pidx    = (const int*)d_in[26];
  float* out = (float*)d_out;

  float* ws = (float*)d_ws;
  float* cin0 = ws;                  // 32*768*10 = 245760
  float* cin1 = cin0 + 245760;       // 245760
  float* cin2 = cin1 + 245760;       // 32*768*6 = 147456
  float* cin3 = cin2 + 147456;       // 147456
  float* part = cin3 + 147456;       // 16*768*192 = 2359296
  float* t0   = part + 2359296;      // 24576
  float* t1   = t0 + 24576;          // 24576
  float* zx   = t1 + 24576;          // 4*32*3336 = 427008
  float* yb   = zx + 427008;         // 49152
  float* sq   = yb + 49152;          // 32
  float* dp   = sq + 32;             // 4*32*768 = 98304

  // ---- CNN frontend ----
  k_patch<<<960, 256, 0, stream>>>(x, patch_w, patch_b, cnn_st + 0, cin0);

  k_conv<10, 6><<<dim3(48, 16), 128, 0, stream>>>(cin0, cnn_w + (size_t)0 * DD * DD * 5, part);
  k_bnrelu<<<96, 256, 0, stream>>>(part, 6, 1, cnn_b + 0 * DD, bn_g + 0 * DD, bn_b + 0 * DD,
                                   bn_rm + 0 * DD, bn_rv + 0 * DD, 0, cin1, 10,
                                   cnn_st + (size_t)1 * BB * DD * 4, pos, pidx);
  k_conv<10, 6><<<dim3(48, 16), 128, 0, stream>>>(cin1, cnn_w + (size_t)1 * DD * DD * 5, part);
  k_bnrelu<<<96, 256, 0, stream>>>(part, 6, 3, cnn_b + 1 * DD, bn_g + 1 * DD, bn_b + 1 * DD,
                                   bn_rm + 1 * DD, bn_rv + 1 * DD, 0, cin2, 6,
                                   cnn_st + (size_t)2 * BB * DD * 4, pos, pidx);
  k_conv<6, 2><<<dim3(48, 16), 128, 0, stream>>>(cin2, cnn_w + (size_t)2 * DD * DD * 5, part);
  k_bnrelu<<<96, 256, 0, stream>>>(part, 2, 1, cnn_b + 2 * DD, bn_g + 2 * DD, bn_b + 2 * DD,
                                   bn_rm + 2 * DD, bn_rv + 2 * DD, 0, cin3, 6,
                                   cnn_st + (size_t)3 * BB * DD * 4, pos, pidx);
  k_conv<6, 2><<<dim3(48, 16), 128, 0, stream>>>(cin3, cnn_w + (size_t)3 * DD * DD * 5, part);
  k_bnrelu<<<96, 256, 0, stream>>>(part, 2, 2, cnn_b + 3 * DD, bn_g + 3 * DD, bn_b + 3 * DD,
                                   bn_rm + 3 * DD, bn_rv + 3 * DD, 1, t0, 0, nullptr, pos, pidx);

  // ---- 12 sequential Mamba layers ----
  float* bufs[2] = {t0, t1};
  for (int L = 0; L < NLAYER; L++) {
    float* rd = (L == 0) ? t0 : bufs[(L + 1) & 1];
    float* wr = (L == 0) ? t1 : bufs[L & 1];
    k_inproj<<<dim3(105, 4), 128, 0, stream>>>(ipw + (size_t)L * RIN * DD, rd, dp, (L > 0) ? 1 : 0,
                                               wr, zx, sq);
    k_ssm<<<768, 256, 0, stream>>>(zx, ssm + (size_t)L * BB * NHi * HDi * DSi,
                                   mcs + (size_t)L * BB * DCONVi * 4, cw + (size_t)L * DCONVi * 4,
                                   cb1 + (size_t)L * DCONVi, alog + L * NHi, dtb + L * NHi,
                                   dpar + L * NHi, yb, sq);
    k_outproj<<<dim3(48, 4), 128, 0, stream>>>(opw + (size_t)L * DD * DIi, yb, zx, sq,
                                               nw + (size_t)L * DIi, dp);
  }

  // ---- final: layernorm + history + logits ----
  k_final<<<32, 256, 0, stream>>>(bufs[(NLAYER - 1) & 1], dp, hf, fcn_g, fcn_b, fc_w, fc_b, pidx,
                                  out);
}